// Round 14
// baseline (397.850 us; speedup 1.0000x reference)
//
#include <hip/hip_runtime.h>
#include <math.h>

#define NSAMP   661500
#define NFRAME  2584
#define NFTOT   20672
#define FPB     8
#define NBLK    2584          // 20672 / 8 exactly

#define EN_OFF    82688
#define CEN_OFF   103360
#define TILT_OFF  124032
#define PITCH_OFF 144704
#define VOI_OFF   165376
#define RC_OFF    186048
#define XDS_OFF   806208

__device__ __forceinline__ float waveReduceSum(float v) {
  #pragma unroll
  for (int m = 1; m < 64; m <<= 1) v += __shfl_xor(v, m, 64);
  return v;
}

__device__ __forceinline__ float blockReduceSum(float v, float* s) {
  v = waveReduceSum(v);
  const int w = threadIdx.x >> 6;
  if ((threadIdx.x & 63) == 0) s[w] = v;
  __syncthreads();
  v = s[0] + s[1] + s[2] + s[3];
  __syncthreads();
  return v;
}

// One fused radix-2^2 double-stage (two radix-2 stages) in registers.
// Identical expressions/order to the proven fft1024p body.
__device__ __forceinline__ void fused_bfly(const float2 a0, const float2 a1,
                                           const float2 a2, const float2 a3,
                                           const float2 w1, float2* o) {
  float2 sA, dA, sB, dB;
  sA.x = a0.x + a2.x; sA.y = a0.y + a2.y;
  { const float dx = a0.x - a2.x, dy = a0.y - a2.y;
    dA.x = dx * w1.x + dy * w1.y;            // d * conj(w1)
    dA.y = dy * w1.x - dx * w1.y; }
  sB.x = a1.x + a3.x; sB.y = a1.y + a3.y;
  { const float dx = a1.x - a3.x, dy = a1.y - a3.y;
    const float wx = -w1.y, wy = w1.x;       // i * w1
    dB.x = dx * wx + dy * wy;
    dB.y = dy * wx - dx * wy; }
  const float w2x = w1.x * w1.x - w1.y * w1.y;   // w1^2
  const float w2y = 2.0f * w1.x * w1.y;
  o[0].x = sA.x + sB.x; o[0].y = sA.y + sB.y;
  { const float dx = sA.x - sB.x, dy = sA.y - sB.y;
    o[2].x = dx * w2x + dy * w2y;
    o[2].y = dy * w2x - dx * w2y; }
  o[1].x = dA.x + dB.x; o[1].y = dA.y + dB.y;
  { const float dx = dA.x - dB.x, dy = dA.y - dB.y;
    o[3].x = dx * w2x + dy * w2y;
    o[3].y = dy * w2x - dx * w2y; }
}

// Remaining 4 fused double-stages (m = 4,16,64,256). Result ends in X.
// Caller must have written the m=1 stage output into X and barriered.
__device__ __forceinline__ void fft4iter(float2* X, float2* Y, const float2* tw, int tid) {
  int m = 4;
  #pragma unroll
  for (int s = 0; s < 4; ++s) {
    const int k  = tid & (m - 1);
    const int jm = tid - k;
    const float2 a0 = X[tid];
    const float2 a1 = X[tid + 256];
    const float2 a2 = X[tid + 512];
    const float2 a3 = X[tid + 768];
    float2 o[4];
    fused_bfly(a0, a1, a2, a3, tw[jm], o);
    const int B = 4 * tid - 3 * k;
    Y[B]         = o[0];
    Y[B + m]     = o[1];
    Y[B + 2 * m] = o[2];
    Y[B + 3 * m] = o[3];
    __syncthreads();
    float2* tmp = X; X = Y; Y = tmp;
    m <<= 2;
  }
}

// f64 Levinson matching the reference recurrence (order 10 -> DK).
template<int ORDER>
__device__ __forceinline__ void levinson_d(const double* r, double* a) {
  double E = r[0];
  a[0] = 1.0;
  #pragma unroll
  for (int m = 1; m <= ORDER; ++m) {
    double acc = r[m];
    #pragma unroll
    for (int i = 1; i < m; ++i) acc += a[i] * r[m - i];
    const double kk = -acc / (E + 1e-9);
    #pragma unroll
    for (int i = 1; i <= (m - 1) / 2; ++i) {
      const double t1 = a[i], t2 = a[m - i];
      a[i]     = t1 + kk * t2;
      a[m - i] = t2 + kk * t1;
    }
    if ((m & 1) == 0) { const double t = a[m >> 1]; a[m >> 1] = t + kk * t; }
    a[m] = kk;
    E *= (1.0 - kk * kk);
  }
}

// f32 Levinson, order 30, rc out only.
__device__ __forceinline__ void levinson_f30(const float* r, float* gk) {
  float a[31];
  float E = r[0];
  a[0] = 1.0f;
  #pragma unroll
  for (int m = 1; m <= 30; ++m) {
    float acc = r[m];
    #pragma unroll
    for (int i = 1; i < m; ++i) acc += a[i] * r[m - i];
    const float kk = -acc / (E + 1e-9f);
    #pragma unroll
    for (int i = 1; i <= (m - 1) / 2; ++i) {
      const float t1 = a[i], t2 = a[m - i];
      a[i]     = t1 + kk * t2;
      a[m - i] = t2 + kk * t1;
    }
    if ((m & 1) == 0) { const float t = a[m >> 1]; a[m >> 1] = t + kk * t; }
    a[m] = kk;
    E *= (1.0f - kk * kk);
    if (gk) gk[m - 1] = kk;
  }
}

__global__ void __launch_bounds__(256, 8)
feat_mono8(const float* __restrict__ x, float* __restrict__ out,
           const int xds_pf, const int nccf_off) {
  __shared__ float2 A[1024];
  __shared__ float2 Bb[1024];
  __shared__ float2 tw[256];
  __shared__ float  sred[12];      // [0..3] pitch pv | [4..7] cs0 | [8..11] cs1
  __shared__ int    sredi[4];
  __shared__ float  stash[FPB][42];  // [phase][0..30]=r30 (normalized), [31..41]=acds
  __shared__ float  aprt[4][11];

  const int tid   = threadIdx.x;
  const int w     = tid >> 6;
  const int lane  = tid & 63;
  const int fbase = blockIdx.x * FPB;

  // ---- per-block prologue (amortized over FPB frames) ----
  {
    const float th = (float)tid * (6.2831853071795864769f / 1024.0f);
    float sn, cn;
    sincosf(th, &sn, &cn);
    tw[tid] = make_float2(cn, sn);
  }
  float wv[4];
  float wsq = 0.0f;
  #pragma unroll
  for (int q = 0; q < 4; ++q) {
    const int n = tid + q * 256;
    const float th = (float)n * (6.2831853071795864769f / 1023.0f);
    const float wn = 0.42f - 0.5f * cosf(th) + 0.08f * cosf(2.0f * th);
    wv[q] = wn;
    wsq += wn * wn;
  }
  float ctab[11];
  #pragma unroll
  for (int l = 0; l < 11; ++l)
    ctab[l] = cosf((float)(tid * l) * (6.2831853071795864769f / 462.0f));
  const float wgt462 = ((tid == 0 || tid == 231) ? 1.0f : 2.0f) * (1.0f / 462.0f);
  __syncthreads();   // tw visible
  const float invn = 1.0f / sqrtf(blockReduceSum(wsq, sred));
  const float2 w1t = tw[tid];   // m=1 stage twiddle (jm = tid)

  #pragma unroll 1
  for (int p = 0; p < FPB; ++p) {
    const int fg = fbase + p;
    const int bb = fg / NFRAME;
    const int fr = fg - bb * NFRAME;
    const float* xb = x + (size_t)bb * NSAMP;

    // ---- load frame + FUSED FFT1 stage-0 (m=1) in registers -> Bb[4t..4t+3]
    {
      float2 z[4];
      #pragma unroll
      for (int q = 0; q < 4; ++q) {
        const int n = tid + q * 256;
        const int g = fr * 256 + n - 512;
        const float xv = (g >= 0 && g < NSAMP) ? xb[g] : 0.0f;
        z[q] = make_float2(xv * wv[q] * invn, xv);  // z = xw + i*xf
      }
      float2 o[4];
      fused_bfly(z[0], z[1], z[2], z[3], w1t, o);
      const int B = 4 * tid;
      Bb[B]     = o[0];
      Bb[B + 1] = o[1];
      Bb[B + 2] = o[2];
      Bb[B + 3] = o[3];
    }
    __syncthreads();   // stage-0 out ready (also: prior phase's A reads done)

    fft4iter(Bb, A, tw, tid);   // FFT1 stages m=4..256; result in Bb

    // unpack: x_ds, centroid partials, own-acds weight (k=tid) — reads Bb only
    float cs0 = 0.0f, cs1 = 0.0f;
    float myPw = 0.0f;
    {
      const int k = tid;
      const float2 Zk = Bb[k];
      const float2 Zn = Bb[(1024 - k) & 1023];
      const float xwr = 0.5f * (Zk.x + Zn.x);
      const float xwi = 0.5f * (Zk.y - Zn.y);
      const float xfr = 0.5f * (Zk.y + Zn.y);
      const float xfi = -0.5f * (Zk.x - Zn.x);
      const float pw = xwr * xwr + xwi * xwi;
      const float pf = xfr * xfr + xfi * xfi;
      const float mg = sqrtf(pf);
      cs0 += mg;
      cs1 += mg * ((float)k * (22050.0f / 1024.0f));
      if (k < 232) {
        myPw = pw;
        if (xds_pf == 232) {
          out[XDS_OFF + (size_t)fg * 232 + k] = xwr;
        } else {
          ((float2*)(out + XDS_OFF))[(size_t)fg * 232 + k] = make_float2(xwr, xwi);
        }
      }
    }
    {
      const int k = tid + 256;
      const float2 Zk = Bb[k];
      const float2 Zn = Bb[1024 - k];
      const float xfr = 0.5f * (Zk.y + Zn.y);
      const float xfi = -0.5f * (Zk.x - Zn.x);
      const float pf = xfr * xfr + xfi * xfi;
      const float mg = sqrtf(pf);
      cs0 += mg;
      cs1 += mg * ((float)k * (22050.0f / 1024.0f));
    }
    if (tid == 0) {
      const int k = 512;
      const float2 Zk = Bb[k];
      const float2 Zn = Bb[512];
      const float xfr = 0.5f * (Zk.y + Zn.y);
      const float xfi = -0.5f * (Zk.x - Zn.x);
      const float pf = xfr * xfr + xfi * xfi;
      const float mg = sqrtf(pf);
      cs0 += mg;
      cs1 += mg * ((float)k * (22050.0f / 1024.0f));
    }

    // ---- pack + FUSED FFT2 stage-0 (m=1) in registers -> A[4t..4t+3]
    {
      float2 in[4];
      #pragma unroll
      for (int q = 0; q < 4; ++q) {
        const int k2 = tid + q * 256;
        const int km = (k2 <= 512) ? k2 : (1024 - k2);
        const float2 Zk = Bb[km];
        const float2 Zn = Bb[(1024 - km) & 1023];
        const float xwr = 0.5f * (Zk.x + Zn.x);
        const float xwi = 0.5f * (Zk.y - Zn.y);
        const float xfr = 0.5f * (Zk.y + Zn.y);
        const float xfi = -0.5f * (Zk.x - Zn.x);
        const float pw = xwr * xwr + xwi * xwi;
        const float pf = xfr * xfr + xfi * xfi;
        in[q] = make_float2(pw * 1024.0f, pf);
      }
      float2 o[4];
      fused_bfly(in[0], in[1], in[2], in[3], w1t, o);
      const int B = 4 * tid;
      A[B]     = o[0];
      A[B + 1] = o[1];
      A[B + 2] = o[2];
      A[B + 3] = o[3];
    }
    __syncthreads();   // all Bb reads done; A (stage-0 out) ready

    fft4iter(A, Bb, tw, tid);   // FFT2 stages m=4..256; result in A
    // A[n].x = 2^20*ac_w[n], A[n].y = 1024*ac_f[n]

    // ---- fused partials: pitch + centroid + acds share ONE barrier ----
    float pv = -3.0e38f;
    int   pl = 1 << 30;
    for (int l = 44 + tid; l <= 441; l += 256) {
      const float v = A[l].y;
      if (v > pv) { pv = v; pl = l; }
    }
    #pragma unroll
    for (int m = 1; m < 64; m <<= 1) {
      const float ov = __shfl_xor(pv, m, 64);
      const int   ol = __shfl_xor(pl, m, 64);
      if (ov > pv || (ov == pv && ol < pl)) { pv = ov; pl = ol; }
    }
    cs0 = waveReduceSum(cs0);
    cs1 = waveReduceSum(cs1);
    if (lane == 0) { sred[w] = pv; sredi[w] = pl; sred[4 + w] = cs0; sred[8 + w] = cs1; }
    const float pwW = myPw * wgt462;
    #pragma unroll
    for (int l = 0; l < 11; ++l) {
      const float t = waveReduceSum(pwW * ctab[l]);
      if (lane == 0) aprt[w][l] = t;
    }
    __syncthreads();

    // finalizers (no barrier after; next phase's post-stage0 barrier orders reuse)
    if (tid == 0) {
      float bv = sred[0]; int bl = sredi[0];
      #pragma unroll
      for (int q = 1; q < 4; ++q)
        if (sred[q] > bv || (sred[q] == bv && sredi[q] < bl)) { bv = sred[q]; bl = sredi[q]; }
      const float ac0  = A[0].y * (1.0f / 1024.0f);
      const float peak = bv * (1.0f / 1024.0f);
      const float nccf = peak / (ac0 + 1e-9f);
      out[PITCH_OFF + fg] = logf(22050.0f / (float)bl);
      out[VOI_OFF + fg]   = (nccf > 0.3f) ? 1.0f : 0.0f;
      out[nccf_off + fg]  = nccf;
      out[EN_OFF + fg]    = 10.0f * log10f(ac0 + 1e-10f);    // Parseval
      const float c0 = sred[4] + sred[5] + sred[6] + sred[7];
      const float c1 = sred[8] + sred[9] + sred[10] + sred[11];
      out[CEN_OFF + fg]   = c1 / (c0 + 1e-10f);
      const float a0 = aprt[0][0] + aprt[1][0] + aprt[2][0] + aprt[3][0];
      const float a1 = aprt[0][1] + aprt[1][1] + aprt[2][1] + aprt[3][1];
      out[TILT_OFF + fg]  = a1 / (a0 + 1e-10f);
    }
    if (tid < 11)
      stash[p][31 + tid] = aprt[0][tid] + aprt[1][tid] + aprt[2][tid] + aprt[3][tid];
    if (tid < 31) stash[p][tid] = A[tid].x * (1.0f / 1048576.0f);  // normalized r30
  }
  __syncthreads();   // stash visible for the tails

  // ---- deferred tails: 8 frames on TWO waves (4 x 10-lane groups each);
  //      waves 2-3 exit. Per-group math bit-identical to round-12 (proven).
  if (w < 2) {
    const int g     = lane / 10;            // 0..6 (g>=4: inactive)
    const int ri    = lane - g * 10;        // 0..9
    const int gbase = g * 10;
    const bool act  = (g < 4);
    const int gg    = act ? (w * 4 + g) : 0;   // frame slot in stash
    const int fg    = fbase + gg;

    levinson_f30(&stash[gg][0],
                 (ri == 0 && act) ? (out + RC_OFF + (size_t)fg * 30) : (float*)nullptr);

    double rds[11], a10[11];
    #pragma unroll
    for (int l = 0; l < 11; ++l) rds[l] = (double)stash[gg][31 + l];
    levinson_d<10>(rds, a10);

    // Durand-Kerner in f64: group lane ri owns root ri; Jacobi via shfl in-group
    double zr = 0.4, zi = 0.9;
    for (int q = 0; q < ri; ++q) {
      const double nr = zr * 0.4 - zi * 0.9;
      zi = zr * 0.9 + zi * 0.4;
      zr = nr;
    }
    for (int it = 0; it < 60; ++it) {
      double pr = 1.0, pi = 0.0;            // Horner, c[0]=1
      #pragma unroll
      for (int q = 1; q <= 10; ++q) {
        const double nr = pr * zr - pi * zi + a10[q];
        pi = pr * zi + pi * zr;
        pr = nr;
      }
      double dr = 1.0, di = 0.0;
      #pragma unroll
      for (int j = 0; j < 10; ++j) {
        const double ozr = __shfl(zr, gbase + j, 64);
        const double ozi = __shfl(zi, gbase + j, 64);
        const double er = (j == ri) ? 1.0 : (zr - ozr);
        const double ei = (j == ri) ? 0.0 : (zi - ozi);
        const double nr = dr * er - di * ei;
        di = dr * ei + di * er;
        dr = nr;
      }
      dr += 1e-12;
      const double inv = 1.0 / (dr * dr + di * di);   // one divide, two mults
      const double qr = (pr * dr + pi * di) * inv;
      const double qi = (pi * dr - pr * di) * inv;
      zr -= qr;
      zi -= qi;
    }
    const double ang = atan2(zi, zr);
    double freq = (ang > 0.0001) ? (ang / 6.283185307179586476925287 * 10000.0) : 5000.0;
    if (ri >= 10) freq = 1.0e300;

    // gather all 10 freqs of the group, then stable 4-min select (lowest j on ties)
    double f[10];
    #pragma unroll
    for (int j = 0; j < 10; ++j) f[j] = __shfl(freq, gbase + j, 64);
    bool used[10];
    #pragma unroll
    for (int j = 0; j < 10; ++j) used[j] = false;
    float o4[4];
    #pragma unroll
    for (int p2 = 0; p2 < 4; ++p2) {
      double mn = 1.0e300;
      int mj = -1;
      #pragma unroll
      for (int j = 0; j < 10; ++j)
        if (!used[j] && f[j] < mn) { mn = f[j]; mj = j; }
      if (mj >= 0) used[mj] = true;
      o4[p2] = (float)mn;
    }
    if (ri == 0 && act) {
      out[(size_t)fg * 4 + 0] = o4[0];
      out[(size_t)fg * 4 + 1] = o4[1];
      out[(size_t)fg * 4 + 2] = o4[2];
      out[(size_t)fg * 4 + 3] = o4[3];
    }
  }
}

extern "C" void kernel_launch(void* const* d_in, const int* in_sizes, int n_in,
                              void* d_out, int out_size, void* d_ws, size_t ws_size,
                              hipStream_t stream) {
  (void)in_sizes; (void)n_in; (void)d_ws; (void)ws_size;
  const float* x = (const float*)d_in[0];
  float* out = (float*)d_out;
  int xds_pf = 232;
  if (out_size >= XDS_OFF + NFTOT * 464 + NFTOT) xds_pf = 464;
  const int nccf_off = XDS_OFF + NFTOT * xds_pf;
  feat_mono8<<<dim3(NBLK), dim3(256), 0, stream>>>(x, out, xds_pf, nccf_off);
}

// Round 15
// 327.713 us; speedup vs baseline: 1.2140x; 1.2140x over previous
//
#include <hip/hip_runtime.h>
#include <math.h>

#define NSAMP   661500
#define NFRAME  2584
#define NFTOT   20672
#define FPB     6
#define NBLK    3446          // ceil(20672/6); last block handles 2 frames

#define EN_OFF    82688
#define CEN_OFF   103360
#define TILT_OFF  124032
#define PITCH_OFF 144704
#define VOI_OFF   165376
#define RC_OFF    186048
#define XDS_OFF   806208

__device__ __forceinline__ float waveReduceSum(float v) {
  #pragma unroll
  for (int m = 1; m < 64; m <<= 1) v += __shfl_xor(v, m, 64);
  return v;
}

__device__ __forceinline__ float blockReduceSum(float v, float* s) {
  v = waveReduceSum(v);
  const int w = threadIdx.x >> 6;
  if ((threadIdx.x & 63) == 0) s[w] = v;
  __syncthreads();
  v = s[0] + s[1] + s[2] + s[3];
  __syncthreads();
  return v;
}

// Stockham radix-2 DIF, N=1024, forward (e^{-i}), TWO stages fused per barrier.
// 5 barriers; result ends in the second buffer. Requires X visible on entry.
__device__ __forceinline__ void fft1024p(float2* X, float2* Y, const float2* tw, int tid) {
  int m = 1;
  #pragma unroll
  for (int s = 0; s < 5; ++s) {
    const int k  = tid & (m - 1);
    const int jm = tid - k;
    const float2 a0 = X[tid];
    const float2 a1 = X[tid + 256];
    const float2 a2 = X[tid + 512];
    const float2 a3 = X[tid + 768];
    const float2 w1 = tw[jm];
    float2 sA, dA, sB, dB;
    sA.x = a0.x + a2.x; sA.y = a0.y + a2.y;
    { const float dx = a0.x - a2.x, dy = a0.y - a2.y;
      dA.x = dx * w1.x + dy * w1.y;            // d * conj(w1)
      dA.y = dy * w1.x - dx * w1.y; }
    sB.x = a1.x + a3.x; sB.y = a1.y + a3.y;
    { const float dx = a1.x - a3.x, dy = a1.y - a3.y;
      const float wx = -w1.y, wy = w1.x;       // i * w1
      dB.x = dx * wx + dy * wy;
      dB.y = dy * wx - dx * wy; }
    const float w2x = w1.x * w1.x - w1.y * w1.y;   // w1^2
    const float w2y = 2.0f * w1.x * w1.y;
    const int B = 4 * tid - 3 * k;
    { float2 o;
      o.x = sA.x + sB.x; o.y = sA.y + sB.y;
      Y[B] = o;
      const float dx = sA.x - sB.x, dy = sA.y - sB.y;
      o.x = dx * w2x + dy * w2y;
      o.y = dy * w2x - dx * w2y;
      Y[B + 2 * m] = o; }
    { float2 o;
      o.x = dA.x + dB.x; o.y = dA.y + dB.y;
      Y[B + m] = o;
      const float dx = dA.x - dB.x, dy = dA.y - dB.y;
      o.x = dx * w2x + dy * w2y;
      o.y = dy * w2x - dx * w2y;
      Y[B + 3 * m] = o; }
    __syncthreads();
    float2* tmp = X; X = Y; Y = tmp;
    m <<= 2;
  }
}

// f64 Levinson matching the reference recurrence (order 10 -> DK).
template<int ORDER>
__device__ __forceinline__ void levinson_d(const double* r, double* a) {
  double E = r[0];
  a[0] = 1.0;
  #pragma unroll
  for (int m = 1; m <= ORDER; ++m) {
    double acc = r[m];
    #pragma unroll
    for (int i = 1; i < m; ++i) acc += a[i] * r[m - i];
    const double kk = -acc / (E + 1e-9);
    #pragma unroll
    for (int i = 1; i <= (m - 1) / 2; ++i) {
      const double t1 = a[i], t2 = a[m - i];
      a[i]     = t1 + kk * t2;
      a[m - i] = t2 + kk * t1;
    }
    if ((m & 1) == 0) { const double t = a[m >> 1]; a[m >> 1] = t + kk * t; }
    a[m] = kk;
    E *= (1.0 - kk * kk);
  }
}

// f32 Levinson, order 30, rc out only (r may be LDS or global).
__device__ __forceinline__ void levinson_f30(const float* r, float* gk) {
  float a[31];
  float E = r[0];
  a[0] = 1.0f;
  #pragma unroll
  for (int m = 1; m <= 30; ++m) {
    float acc = r[m];
    #pragma unroll
    for (int i = 1; i < m; ++i) acc += a[i] * r[m - i];
    const float kk = -acc / (E + 1e-9f);
    #pragma unroll
    for (int i = 1; i <= (m - 1) / 2; ++i) {
      const float t1 = a[i], t2 = a[m - i];
      a[i]     = t1 + kk * t2;
      a[m - i] = t2 + kk * t1;
    }
    if ((m & 1) == 0) { const float t = a[m >> 1]; a[m >> 1] = t + kk * t; }
    a[m] = kk;
    E *= (1.0f - kk * kk);
    if (gk) gk[m - 1] = kk;
  }
}

// Shared tail body: one 10-lane group handles one frame. Bit-identical to R11/R12.
__device__ __forceinline__ void tail_group(const float* st, float* out,
                                           int frame, int ri, int gbase, bool act) {
  levinson_f30(st, (ri == 0 && act) ? (out + RC_OFF + (size_t)frame * 30)
                                    : (float*)nullptr);

  double rds[11], a10[11];
  #pragma unroll
  for (int l = 0; l < 11; ++l) rds[l] = (double)st[31 + l];
  levinson_d<10>(rds, a10);

  double zr = 0.4, zi = 0.9;
  for (int q = 0; q < ri; ++q) {
    const double nr = zr * 0.4 - zi * 0.9;
    zi = zr * 0.9 + zi * 0.4;
    zr = nr;
  }
  for (int it = 0; it < 60; ++it) {
    double pr = 1.0, pi = 0.0;            // Horner, c[0]=1
    #pragma unroll
    for (int q = 1; q <= 10; ++q) {
      const double nr = pr * zr - pi * zi + a10[q];
      pi = pr * zi + pi * zr;
      pr = nr;
    }
    double dr = 1.0, di = 0.0;
    #pragma unroll
    for (int j = 0; j < 10; ++j) {
      const double ozr = __shfl(zr, gbase + j, 64);
      const double ozi = __shfl(zi, gbase + j, 64);
      const double er = (j == ri) ? 1.0 : (zr - ozr);
      const double ei = (j == ri) ? 0.0 : (zi - ozi);
      const double nr = dr * er - di * ei;
      di = dr * ei + di * er;
      dr = nr;
    }
    dr += 1e-12;
    const double inv = 1.0 / (dr * dr + di * di);   // one divide, two mults
    const double qr = (pr * dr + pi * di) * inv;
    const double qi = (pi * dr - pr * di) * inv;
    zr -= qr;
    zi -= qi;
  }
  const double ang = atan2(zi, zr);
  double freq = (ang > 0.0001) ? (ang / 6.283185307179586476925287 * 10000.0) : 5000.0;
  if (ri >= 10) freq = 1.0e300;

  double f[10];
  #pragma unroll
  for (int j = 0; j < 10; ++j) f[j] = __shfl(freq, gbase + j, 64);
  bool used[10];
  #pragma unroll
  for (int j = 0; j < 10; ++j) used[j] = false;
  float o4[4];
  #pragma unroll
  for (int p2 = 0; p2 < 4; ++p2) {
    double mn = 1.0e300;
    int mj = -1;
    #pragma unroll
    for (int j = 0; j < 10; ++j)
      if (!used[j] && f[j] < mn) { mn = f[j]; mj = j; }
    if (mj >= 0) used[mj] = true;
    o4[p2] = (float)mn;
  }
  if (ri == 0 && act) {
    out[(size_t)frame * 4 + 0] = o4[0];
    out[(size_t)frame * 4 + 1] = o4[1];
    out[(size_t)frame * 4 + 2] = o4[2];
    out[(size_t)frame * 4 + 3] = o4[3];
  }
}

// ============ K1: front (R12 structure), stash -> ws, nt x_ds stores ============
__global__ void __launch_bounds__(256, 8)
feat_front(const float* __restrict__ x, float* __restrict__ out,
           float* __restrict__ ws, const int xds_pf, const int nccf_off) {
  __shared__ float2 A[1024];
  __shared__ float2 Bb[1024];
  __shared__ float2 tw[256];
  __shared__ float  sred[12];
  __shared__ int    sredi[4];
  __shared__ float  aprt[4][11];

  const int tid   = threadIdx.x;
  const int w     = tid >> 6;
  const int lane  = tid & 63;
  const int fbase = blockIdx.x * FPB;
  const int np    = (fbase + FPB <= NFTOT) ? FPB : (NFTOT - fbase);

  {
    const float th = (float)tid * (6.2831853071795864769f / 1024.0f);
    float sn, cn;
    sincosf(th, &sn, &cn);
    tw[tid] = make_float2(cn, sn);
  }
  float wv[4];
  float wsq = 0.0f;
  #pragma unroll
  for (int q = 0; q < 4; ++q) {
    const int n = tid + q * 256;
    const float th = (float)n * (6.2831853071795864769f / 1023.0f);
    const float wn = 0.42f - 0.5f * cosf(th) + 0.08f * cosf(2.0f * th);
    wv[q] = wn;
    wsq += wn * wn;
  }
  float ctab[11];
  #pragma unroll
  for (int l = 0; l < 11; ++l)
    ctab[l] = cosf((float)(tid * l) * (6.2831853071795864769f / 462.0f));
  const float wgt462 = ((tid == 0 || tid == 231) ? 1.0f : 2.0f) * (1.0f / 462.0f);
  __syncthreads();
  const float invn = 1.0f / sqrtf(blockReduceSum(wsq, sred));

  #pragma unroll 1
  for (int p = 0; p < np; ++p) {
    const int fg = fbase + p;
    const int bb = fg / NFRAME;
    const int fr = fg - bb * NFRAME;
    const float* xb = x + (size_t)bb * NSAMP;

    #pragma unroll
    for (int q = 0; q < 4; ++q) {
      const int n = tid + q * 256;
      const int g = fr * 256 + n - 512;
      const float xv = (g >= 0 && g < NSAMP) ? xb[g] : 0.0f;
      A[n] = make_float2(xv * wv[q] * invn, xv);
    }
    __syncthreads();

    fft1024p(A, Bb, tw, tid);  // spectra -> Bb

    float cs0 = 0.0f, cs1 = 0.0f;
    float myPw = 0.0f;
    {
      const int k = tid;
      const float2 Zk = Bb[k];
      const float2 Zn = Bb[(1024 - k) & 1023];
      const float xwr = 0.5f * (Zk.x + Zn.x);
      const float xwi = 0.5f * (Zk.y - Zn.y);
      const float xfr = 0.5f * (Zk.y + Zn.y);
      const float xfi = -0.5f * (Zk.x - Zn.x);
      const float pw = xwr * xwr + xwi * xwi;
      const float pf = xfr * xfr + xfi * xfi;
      const float mg = sqrtf(pf);
      cs0 += mg;
      cs1 += mg * ((float)k * (22050.0f / 1024.0f));
      if (k < 232) {
        myPw = pw;
        if (xds_pf == 232) {
          __builtin_nontemporal_store(xwr, &out[XDS_OFF + (size_t)fg * 232 + k]);
        } else {
          float* dst = out + XDS_OFF + ((size_t)fg * 232 + k) * 2;
          __builtin_nontemporal_store(xwr, dst);
          __builtin_nontemporal_store(xwi, dst + 1);
        }
      }
    }
    {
      const int k = tid + 256;
      const float2 Zk = Bb[k];
      const float2 Zn = Bb[1024 - k];
      const float xfr = 0.5f * (Zk.y + Zn.y);
      const float xfi = -0.5f * (Zk.x - Zn.x);
      const float pf = xfr * xfr + xfi * xfi;
      const float mg = sqrtf(pf);
      cs0 += mg;
      cs1 += mg * ((float)k * (22050.0f / 1024.0f));
    }
    if (tid == 0) {
      const int k = 512;
      const float2 Zk = Bb[k];
      const float2 Zn = Bb[512];
      const float xfr = 0.5f * (Zk.y + Zn.y);
      const float xfi = -0.5f * (Zk.x - Zn.x);
      const float pf = xfr * xfr + xfi * xfi;
      const float mg = sqrtf(pf);
      cs0 += mg;
      cs1 += mg * ((float)k * (22050.0f / 1024.0f));
    }

    #pragma unroll
    for (int q = 0; q < 4; ++q) {
      const int k2 = tid + q * 256;
      const int km = (k2 <= 512) ? k2 : (1024 - k2);
      const float2 Zk = Bb[km];
      const float2 Zn = Bb[(1024 - km) & 1023];
      const float xwr = 0.5f * (Zk.x + Zn.x);
      const float xwi = 0.5f * (Zk.y - Zn.y);
      const float xfr = 0.5f * (Zk.y + Zn.y);
      const float xfi = -0.5f * (Zk.x - Zn.x);
      const float pw = xwr * xwr + xwi * xwi;
      const float pf = xfr * xfr + xfi * xfi;
      A[k2] = make_float2(pw * 1024.0f, pf);
    }
    __syncthreads();

    fft1024p(A, Bb, tw, tid);  // Bb[n].x = 2^20*ac_w[n], Bb[n].y = 1024*ac_f[n]

    float pv = -3.0e38f;
    int   pl = 1 << 30;
    for (int l = 44 + tid; l <= 441; l += 256) {
      const float v = Bb[l].y;
      if (v > pv) { pv = v; pl = l; }
    }
    #pragma unroll
    for (int m = 1; m < 64; m <<= 1) {
      const float ov = __shfl_xor(pv, m, 64);
      const int   ol = __shfl_xor(pl, m, 64);
      if (ov > pv || (ov == pv && ol < pl)) { pv = ov; pl = ol; }
    }
    cs0 = waveReduceSum(cs0);
    cs1 = waveReduceSum(cs1);
    if (lane == 0) { sred[w] = pv; sredi[w] = pl; sred[4 + w] = cs0; sred[8 + w] = cs1; }
    const float pwW = myPw * wgt462;
    #pragma unroll
    for (int l = 0; l < 11; ++l) {
      const float t = waveReduceSum(pwW * ctab[l]);
      if (lane == 0) aprt[w][l] = t;
    }
    __syncthreads();

    if (tid == 0) {
      float bv = sred[0]; int bl = sredi[0];
      #pragma unroll
      for (int q = 1; q < 4; ++q)
        if (sred[q] > bv || (sred[q] == bv && sredi[q] < bl)) { bv = sred[q]; bl = sredi[q]; }
      const float ac0  = Bb[0].y * (1.0f / 1024.0f);
      const float peak = bv * (1.0f / 1024.0f);
      const float nccf = peak / (ac0 + 1e-9f);
      out[PITCH_OFF + fg] = logf(22050.0f / (float)bl);
      out[VOI_OFF + fg]   = (nccf > 0.3f) ? 1.0f : 0.0f;
      out[nccf_off + fg]  = nccf;
      out[EN_OFF + fg]    = 10.0f * log10f(ac0 + 1e-10f);    // Parseval
      const float c0 = sred[4] + sred[5] + sred[6] + sred[7];
      const float c1 = sred[8] + sred[9] + sred[10] + sred[11];
      out[CEN_OFF + fg]   = c1 / (c0 + 1e-10f);
      const float a0 = aprt[0][0] + aprt[1][0] + aprt[2][0] + aprt[3][0];
      const float a1 = aprt[0][1] + aprt[1][1] + aprt[2][1] + aprt[3][1];
      out[TILT_OFF + fg]  = a1 / (a0 + 1e-10f);
    }
    if (tid < 11)
      ws[(size_t)fg * 42 + 31 + tid] =
          aprt[0][tid] + aprt[1][tid] + aprt[2][tid] + aprt[3][tid];
    if (tid < 31)
      ws[(size_t)fg * 42 + tid] = Bb[tid].x * (1.0f / 1048576.0f);
  }
}

// ============ K2: tails, 24 frames/block (4 waves x 6 ten-lane groups) ============
__global__ void __launch_bounds__(256)
feat_tail(const float* __restrict__ ws, float* __restrict__ out) {
  const int tid  = threadIdx.x;
  const int w    = tid >> 6;
  const int lane = tid & 63;
  const int g    = lane / 10;            // 0..6 (g=6: lanes 60-63, inactive)
  const int ri   = lane - g * 10;
  const int gbase = g * 10;
  int frame = blockIdx.x * 24 + w * 6 + ((g < 6) ? g : 5);
  const bool act = (g < 6) && (frame < NFTOT);
  if (frame >= NFTOT) frame = NFTOT - 1;

  float st[42];
  #pragma unroll
  for (int j = 0; j < 42; ++j) st[j] = ws[(size_t)frame * 42 + j];

  tail_group(st, out, frame, ri, gbase, act);
}

// ============ Fallback: verbatim round-12 monolith (proven PASS) ============
__global__ void __launch_bounds__(256, 8)
feat_mono_fb(const float* __restrict__ x, float* __restrict__ out,
             const int xds_pf, const int nccf_off) {
  __shared__ float2 A[1024];
  __shared__ float2 Bb[1024];
  __shared__ float2 tw[256];
  __shared__ float  sred[12];
  __shared__ int    sredi[4];
  __shared__ float  stash[FPB][42];
  __shared__ float  aprt[4][11];

  const int tid   = threadIdx.x;
  const int w     = tid >> 6;
  const int lane  = tid & 63;
  const int fbase = blockIdx.x * FPB;
  const int np    = (fbase + FPB <= NFTOT) ? FPB : (NFTOT - fbase);

  {
    const float th = (float)tid * (6.2831853071795864769f / 1024.0f);
    float sn, cn;
    sincosf(th, &sn, &cn);
    tw[tid] = make_float2(cn, sn);
  }
  float wv[4];
  float wsq = 0.0f;
  #pragma unroll
  for (int q = 0; q < 4; ++q) {
    const int n = tid + q * 256;
    const float th = (float)n * (6.2831853071795864769f / 1023.0f);
    const float wn = 0.42f - 0.5f * cosf(th) + 0.08f * cosf(2.0f * th);
    wv[q] = wn;
    wsq += wn * wn;
  }
  float ctab[11];
  #pragma unroll
  for (int l = 0; l < 11; ++l)
    ctab[l] = cosf((float)(tid * l) * (6.2831853071795864769f / 462.0f));
  const float wgt462 = ((tid == 0 || tid == 231) ? 1.0f : 2.0f) * (1.0f / 462.0f);
  __syncthreads();
  const float invn = 1.0f / sqrtf(blockReduceSum(wsq, sred));

  #pragma unroll 1
  for (int p = 0; p < np; ++p) {
    const int fg = fbase + p;
    const int bb = fg / NFRAME;
    const int fr = fg - bb * NFRAME;
    const float* xb = x + (size_t)bb * NSAMP;

    #pragma unroll
    for (int q = 0; q < 4; ++q) {
      const int n = tid + q * 256;
      const int g = fr * 256 + n - 512;
      const float xv = (g >= 0 && g < NSAMP) ? xb[g] : 0.0f;
      A[n] = make_float2(xv * wv[q] * invn, xv);
    }
    __syncthreads();

    fft1024p(A, Bb, tw, tid);

    float cs0 = 0.0f, cs1 = 0.0f;
    float myPw = 0.0f;
    {
      const int k = tid;
      const float2 Zk = Bb[k];
      const float2 Zn = Bb[(1024 - k) & 1023];
      const float xwr = 0.5f * (Zk.x + Zn.x);
      const float xwi = 0.5f * (Zk.y - Zn.y);
      const float xfr = 0.5f * (Zk.y + Zn.y);
      const float xfi = -0.5f * (Zk.x - Zn.x);
      const float pw = xwr * xwr + xwi * xwi;
      const float pf = xfr * xfr + xfi * xfi;
      const float mg = sqrtf(pf);
      cs0 += mg;
      cs1 += mg * ((float)k * (22050.0f / 1024.0f));
      if (k < 232) {
        myPw = pw;
        if (xds_pf == 232) {
          out[XDS_OFF + (size_t)fg * 232 + k] = xwr;
        } else {
          ((float2*)(out + XDS_OFF))[(size_t)fg * 232 + k] = make_float2(xwr, xwi);
        }
      }
    }
    {
      const int k = tid + 256;
      const float2 Zk = Bb[k];
      const float2 Zn = Bb[1024 - k];
      const float xfr = 0.5f * (Zk.y + Zn.y);
      const float xfi = -0.5f * (Zk.x - Zn.x);
      const float pf = xfr * xfr + xfi * xfi;
      const float mg = sqrtf(pf);
      cs0 += mg;
      cs1 += mg * ((float)k * (22050.0f / 1024.0f));
    }
    if (tid == 0) {
      const int k = 512;
      const float2 Zk = Bb[k];
      const float2 Zn = Bb[512];
      const float xfr = 0.5f * (Zk.y + Zn.y);
      const float xfi = -0.5f * (Zk.x - Zn.x);
      const float pf = xfr * xfr + xfi * xfi;
      const float mg = sqrtf(pf);
      cs0 += mg;
      cs1 += mg * ((float)k * (22050.0f / 1024.0f));
    }

    #pragma unroll
    for (int q = 0; q < 4; ++q) {
      const int k2 = tid + q * 256;
      const int km = (k2 <= 512) ? k2 : (1024 - k2);
      const float2 Zk = Bb[km];
      const float2 Zn = Bb[(1024 - km) & 1023];
      const float xwr = 0.5f * (Zk.x + Zn.x);
      const float xwi = 0.5f * (Zk.y - Zn.y);
      const float xfr = 0.5f * (Zk.y + Zn.y);
      const float xfi = -0.5f * (Zk.x - Zn.x);
      const float pw = xwr * xwr + xwi * xwi;
      const float pf = xfr * xfr + xfi * xfi;
      A[k2] = make_float2(pw * 1024.0f, pf);
    }
    __syncthreads();

    fft1024p(A, Bb, tw, tid);

    float pv = -3.0e38f;
    int   pl = 1 << 30;
    for (int l = 44 + tid; l <= 441; l += 256) {
      const float v = Bb[l].y;
      if (v > pv) { pv = v; pl = l; }
    }
    #pragma unroll
    for (int m = 1; m < 64; m <<= 1) {
      const float ov = __shfl_xor(pv, m, 64);
      const int   ol = __shfl_xor(pl, m, 64);
      if (ov > pv || (ov == pv && ol < pl)) { pv = ov; pl = ol; }
    }
    cs0 = waveReduceSum(cs0);
    cs1 = waveReduceSum(cs1);
    if (lane == 0) { sred[w] = pv; sredi[w] = pl; sred[4 + w] = cs0; sred[8 + w] = cs1; }
    const float pwW = myPw * wgt462;
    #pragma unroll
    for (int l = 0; l < 11; ++l) {
      const float t = waveReduceSum(pwW * ctab[l]);
      if (lane == 0) aprt[w][l] = t;
    }
    __syncthreads();

    if (tid == 0) {
      float bv = sred[0]; int bl = sredi[0];
      #pragma unroll
      for (int q = 1; q < 4; ++q)
        if (sred[q] > bv || (sred[q] == bv && sredi[q] < bl)) { bv = sred[q]; bl = sredi[q]; }
      const float ac0  = Bb[0].y * (1.0f / 1024.0f);
      const float peak = bv * (1.0f / 1024.0f);
      const float nccf = peak / (ac0 + 1e-9f);
      out[PITCH_OFF + fg] = logf(22050.0f / (float)bl);
      out[VOI_OFF + fg]   = (nccf > 0.3f) ? 1.0f : 0.0f;
      out[nccf_off + fg]  = nccf;
      out[EN_OFF + fg]    = 10.0f * log10f(ac0 + 1e-10f);
      const float c0 = sred[4] + sred[5] + sred[6] + sred[7];
      const float c1 = sred[8] + sred[9] + sred[10] + sred[11];
      out[CEN_OFF + fg]   = c1 / (c0 + 1e-10f);
      const float a0 = aprt[0][0] + aprt[1][0] + aprt[2][0] + aprt[3][0];
      const float a1 = aprt[0][1] + aprt[1][1] + aprt[2][1] + aprt[3][1];
      out[TILT_OFF + fg]  = a1 / (a0 + 1e-10f);
    }
    if (tid < 11)
      stash[p][31 + tid] = aprt[0][tid] + aprt[1][tid] + aprt[2][tid] + aprt[3][tid];
    if (tid < 31) stash[p][tid] = Bb[tid].x * (1.0f / 1048576.0f);
  }
  __syncthreads();

  if (w == 0) {
    const int g     = lane / 10;
    const int ri    = lane - g * 10;
    const int gbase = g * 10;
    const int gg    = (g < FPB) ? g : (FPB - 1);
    const bool act  = (g < np);
    const int fg    = fbase + gg;
    tail_group(&stash[gg][0], out, fg, ri, gbase, act);
  }
}

extern "C" void kernel_launch(void* const* d_in, const int* in_sizes, int n_in,
                              void* d_out, int out_size, void* d_ws, size_t ws_size,
                              hipStream_t stream) {
  (void)in_sizes; (void)n_in;
  const float* x = (const float*)d_in[0];
  float* out = (float*)d_out;
  int xds_pf = 232;
  if (out_size >= XDS_OFF + NFTOT * 464 + NFTOT) xds_pf = 464;
  const int nccf_off = XDS_OFF + NFTOT * xds_pf;

  const size_t need = (size_t)NFTOT * 42 * 4;   // 3,472,896 B
  if (d_ws != nullptr && ws_size >= need) {
    float* ws = (float*)d_ws;
    feat_front<<<dim3(NBLK), dim3(256), 0, stream>>>(x, out, ws, xds_pf, nccf_off);
    feat_tail<<<dim3((NFTOT + 23) / 24), dim3(256), 0, stream>>>(ws, out);
  } else {
    feat_mono_fb<<<dim3(NBLK), dim3(256), 0, stream>>>(x, out, xds_pf, nccf_off);
  }
}

// Round 16
// 318.939 us; speedup vs baseline: 1.2474x; 1.0275x over previous
//
#include <hip/hip_runtime.h>
#include <math.h>

#define NSAMP   661500
#define NFRAME  2584
#define NFTOT   20672
#define FPB     6
#define NBLK    3446          // ceil(20672/6); last block handles 2 frames

#define EN_OFF    82688
#define CEN_OFF   103360
#define TILT_OFF  124032
#define PITCH_OFF 144704
#define VOI_OFF   165376
#define RC_OFF    186048
#define XDS_OFF   806208

__device__ __forceinline__ float waveReduceSum(float v) {
  #pragma unroll
  for (int m = 1; m < 64; m <<= 1) v += __shfl_xor(v, m, 64);
  return v;
}

__device__ __forceinline__ float blockReduceSum(float v, float* s) {
  v = waveReduceSum(v);
  const int w = threadIdx.x >> 6;
  if ((threadIdx.x & 63) == 0) s[w] = v;
  __syncthreads();
  v = s[0] + s[1] + s[2] + s[3];
  __syncthreads();
  return v;
}

// Stockham radix-2 DIF, N=1024, forward (e^{-i}), TWO stages fused per barrier.
// 5 barriers; result ends in the second buffer. Requires X visible on entry.
__device__ __forceinline__ void fft1024p(float2* X, float2* Y, const float2* tw, int tid) {
  int m = 1;
  #pragma unroll
  for (int s = 0; s < 5; ++s) {
    const int k  = tid & (m - 1);
    const int jm = tid - k;
    const float2 a0 = X[tid];
    const float2 a1 = X[tid + 256];
    const float2 a2 = X[tid + 512];
    const float2 a3 = X[tid + 768];
    const float2 w1 = tw[jm];
    float2 sA, dA, sB, dB;
    sA.x = a0.x + a2.x; sA.y = a0.y + a2.y;
    { const float dx = a0.x - a2.x, dy = a0.y - a2.y;
      dA.x = dx * w1.x + dy * w1.y;            // d * conj(w1)
      dA.y = dy * w1.x - dx * w1.y; }
    sB.x = a1.x + a3.x; sB.y = a1.y + a3.y;
    { const float dx = a1.x - a3.x, dy = a1.y - a3.y;
      const float wx = -w1.y, wy = w1.x;       // i * w1
      dB.x = dx * wx + dy * wy;
      dB.y = dy * wx - dx * wy; }
    const float w2x = w1.x * w1.x - w1.y * w1.y;   // w1^2
    const float w2y = 2.0f * w1.x * w1.y;
    const int B = 4 * tid - 3 * k;
    { float2 o;
      o.x = sA.x + sB.x; o.y = sA.y + sB.y;
      Y[B] = o;
      const float dx = sA.x - sB.x, dy = sA.y - sB.y;
      o.x = dx * w2x + dy * w2y;
      o.y = dy * w2x - dx * w2y;
      Y[B + 2 * m] = o; }
    { float2 o;
      o.x = dA.x + dB.x; o.y = dA.y + dB.y;
      Y[B + m] = o;
      const float dx = dA.x - dB.x, dy = dA.y - dB.y;
      o.x = dx * w2x + dy * w2y;
      o.y = dy * w2x - dx * w2y;
      Y[B + 3 * m] = o; }
    __syncthreads();
    float2* tmp = X; X = Y; Y = tmp;
    m <<= 2;
  }
}

// f64 Levinson matching the reference recurrence (order 10 -> DK).
template<int ORDER>
__device__ __forceinline__ void levinson_d(const double* r, double* a) {
  double E = r[0];
  a[0] = 1.0;
  #pragma unroll
  for (int m = 1; m <= ORDER; ++m) {
    double acc = r[m];
    #pragma unroll
    for (int i = 1; i < m; ++i) acc += a[i] * r[m - i];
    const double kk = -acc / (E + 1e-9);
    #pragma unroll
    for (int i = 1; i <= (m - 1) / 2; ++i) {
      const double t1 = a[i], t2 = a[m - i];
      a[i]     = t1 + kk * t2;
      a[m - i] = t2 + kk * t1;
    }
    if ((m & 1) == 0) { const double t = a[m >> 1]; a[m >> 1] = t + kk * t; }
    a[m] = kk;
    E *= (1.0 - kk * kk);
  }
}

// f32 Levinson, order 30, rc out only (r may be LDS or global or regs).
__device__ __forceinline__ void levinson_f30(const float* r, float* gk) {
  float a[31];
  float E = r[0];
  a[0] = 1.0f;
  #pragma unroll
  for (int m = 1; m <= 30; ++m) {
    float acc = r[m];
    #pragma unroll
    for (int i = 1; i < m; ++i) acc += a[i] * r[m - i];
    const float kk = -acc / (E + 1e-9f);
    #pragma unroll
    for (int i = 1; i <= (m - 1) / 2; ++i) {
      const float t1 = a[i], t2 = a[m - i];
      a[i]     = t1 + kk * t2;
      a[m - i] = t2 + kk * t1;
    }
    if ((m & 1) == 0) { const float t = a[m >> 1]; a[m >> 1] = t + kk * t; }
    a[m] = kk;
    E *= (1.0f - kk * kk);
    if (gk) gk[m - 1] = kk;
  }
}

// Shared tail body: one 10-lane group handles one frame. Same arithmetic order
// as R11/R12; f64 shfls hoisted out of the dependency chain (values identical).
__device__ __forceinline__ void tail_group(const float* st, float* out,
                                           int frame, int ri, int gbase, bool act) {
  levinson_f30(st, (ri == 0 && act) ? (out + RC_OFF + (size_t)frame * 30)
                                    : (float*)nullptr);

  double rds[11], a10[11];
  #pragma unroll
  for (int l = 0; l < 11; ++l) rds[l] = (double)st[31 + l];
  levinson_d<10>(rds, a10);

  double zr = 0.4, zi = 0.9;
  for (int q = 0; q < ri; ++q) {
    const double nr = zr * 0.4 - zi * 0.9;
    zi = zr * 0.9 + zi * 0.4;
    zr = nr;
  }
  #pragma unroll 1
  for (int it = 0; it < 60; ++it) {
    double ozr[10], ozi[10];                // batched: off the dependency chain
    #pragma unroll
    for (int j = 0; j < 10; ++j) {
      ozr[j] = __shfl(zr, gbase + j, 64);
      ozi[j] = __shfl(zi, gbase + j, 64);
    }
    double pr = 1.0, pi = 0.0;              // Horner, c[0]=1
    #pragma unroll
    for (int q = 1; q <= 10; ++q) {
      const double nr = pr * zr - pi * zi + a10[q];
      pi = pr * zi + pi * zr;
      pr = nr;
    }
    double dr = 1.0, di = 0.0;
    #pragma unroll
    for (int j = 0; j < 10; ++j) {
      const double er = (j == ri) ? 1.0 : (zr - ozr[j]);
      const double ei = (j == ri) ? 0.0 : (zi - ozi[j]);
      const double nr = dr * er - di * ei;
      di = dr * ei + di * er;
      dr = nr;
    }
    dr += 1e-12;
    const double inv = 1.0 / (dr * dr + di * di);   // one divide, two mults
    const double qr = (pr * dr + pi * di) * inv;
    const double qi = (pi * dr - pr * di) * inv;
    zr -= qr;
    zi -= qi;
  }
  const double ang = atan2(zi, zr);
  double freq = (ang > 0.0001) ? (ang / 6.283185307179586476925287 * 10000.0) : 5000.0;
  if (ri >= 10) freq = 1.0e300;

  double f[10];
  #pragma unroll
  for (int j = 0; j < 10; ++j) f[j] = __shfl(freq, gbase + j, 64);
  bool used[10];
  #pragma unroll
  for (int j = 0; j < 10; ++j) used[j] = false;
  float o4[4];
  #pragma unroll
  for (int p2 = 0; p2 < 4; ++p2) {
    double mn = 1.0e300;
    int mj = -1;
    #pragma unroll
    for (int j = 0; j < 10; ++j)
      if (!used[j] && f[j] < mn) { mn = f[j]; mj = j; }
    if (mj >= 0) used[mj] = true;
    o4[p2] = (float)mn;
  }
  if (ri == 0 && act) {
    out[(size_t)frame * 4 + 0] = o4[0];
    out[(size_t)frame * 4 + 1] = o4[1];
    out[(size_t)frame * 4 + 2] = o4[2];
    out[(size_t)frame * 4 + 3] = o4[3];
  }
}

// ============ K1: front; pack phase derived from unpack registers ============
__global__ void __launch_bounds__(256, 8)
feat_front(const float* __restrict__ x, float* __restrict__ out,
           float* __restrict__ ws, const int xds_pf, const int nccf_off) {
  __shared__ float2 A[1024];
  __shared__ float2 Bb[1024];
  __shared__ float2 tw[256];
  __shared__ float  sred[12];
  __shared__ int    sredi[4];
  __shared__ float  aprt[4][11];

  const int tid   = threadIdx.x;
  const int w     = tid >> 6;
  const int lane  = tid & 63;
  const int fbase = blockIdx.x * FPB;
  const int np    = (fbase + FPB <= NFTOT) ? FPB : (NFTOT - fbase);

  {
    const float th = (float)tid * (6.2831853071795864769f / 1024.0f);
    float sn, cn;
    sincosf(th, &sn, &cn);
    tw[tid] = make_float2(cn, sn);
  }
  float wv[4];
  float wsq = 0.0f;
  #pragma unroll
  for (int q = 0; q < 4; ++q) {
    const int n = tid + q * 256;
    const float th = (float)n * (6.2831853071795864769f / 1023.0f);
    const float wn = 0.42f - 0.5f * cosf(th) + 0.08f * cosf(2.0f * th);
    wv[q] = wn;
    wsq += wn * wn;
  }
  float ctab[11];
  #pragma unroll
  for (int l = 0; l < 11; ++l)
    ctab[l] = cosf((float)(tid * l) * (6.2831853071795864769f / 462.0f));
  const float wgt462 = ((tid == 0 || tid == 231) ? 1.0f : 2.0f) * (1.0f / 462.0f);
  __syncthreads();
  const float invn = 1.0f / sqrtf(blockReduceSum(wsq, sred));

  #pragma unroll 1
  for (int p = 0; p < np; ++p) {
    const int fg = fbase + p;
    const int bb = fg / NFRAME;
    const int fr = fg - bb * NFRAME;
    const float* xb = x + (size_t)bb * NSAMP;

    #pragma unroll
    for (int q = 0; q < 4; ++q) {
      const int n = tid + q * 256;
      const int g = fr * 256 + n - 512;
      const float xv = (g >= 0 && g < NSAMP) ? xb[g] : 0.0f;
      A[n] = make_float2(xv * wv[q] * invn, xv);
    }
    __syncthreads();

    fft1024p(A, Bb, tw, tid);  // spectra -> Bb

    // unpack at k=tid, k=tid+256 (+k=512 on tid 0): x_ds, centroid, pw/pf kept
    float cs0 = 0.0f, cs1 = 0.0f;
    float myPw = 0.0f;
    float pw0, pf0, pw1, pf1;
    {
      const int k = tid;
      const float2 Zk = Bb[k];
      const float2 Zn = Bb[(1024 - k) & 1023];
      const float xwr = 0.5f * (Zk.x + Zn.x);
      const float xwi = 0.5f * (Zk.y - Zn.y);
      const float xfr = 0.5f * (Zk.y + Zn.y);
      const float xfi = -0.5f * (Zk.x - Zn.x);
      pw0 = xwr * xwr + xwi * xwi;
      pf0 = xfr * xfr + xfi * xfi;
      const float mg = sqrtf(pf0);
      cs0 += mg;
      cs1 += mg * ((float)k * (22050.0f / 1024.0f));
      if (k < 232) {
        myPw = pw0;
        if (xds_pf == 232) {
          __builtin_nontemporal_store(xwr, &out[XDS_OFF + (size_t)fg * 232 + k]);
        } else {
          float* dst = out + XDS_OFF + ((size_t)fg * 232 + k) * 2;
          __builtin_nontemporal_store(xwr, dst);
          __builtin_nontemporal_store(xwi, dst + 1);
        }
      }
    }
    {
      const int k = tid + 256;
      const float2 Zk = Bb[k];
      const float2 Zn = Bb[1024 - k];
      const float xwr = 0.5f * (Zk.x + Zn.x);
      const float xwi = 0.5f * (Zk.y - Zn.y);
      const float xfr = 0.5f * (Zk.y + Zn.y);
      const float xfi = -0.5f * (Zk.x - Zn.x);
      pw1 = xwr * xwr + xwi * xwi;
      pf1 = xfr * xfr + xfi * xfi;
      const float mg = sqrtf(pf1);
      cs0 += mg;
      cs1 += mg * ((float)k * (22050.0f / 1024.0f));
    }
    if (tid == 0) {
      const int k = 512;
      const float2 Zk = Bb[k];
      const float2 Zn = Bb[512];
      const float xwr = 0.5f * (Zk.x + Zn.x);
      const float xwi = 0.5f * (Zk.y - Zn.y);
      const float xfr = 0.5f * (Zk.y + Zn.y);
      const float xfi = -0.5f * (Zk.x - Zn.x);
      const float pw = xwr * xwr + xwi * xwi;
      const float pf = xfr * xfr + xfi * xfi;
      const float mg = sqrtf(pf);
      cs0 += mg;
      cs1 += mg * ((float)k * (22050.0f / 1024.0f));
      A[512] = make_float2(pw * 1024.0f, pf);   // pack value at k2=512
    }

    // pack FFT2 input purely from registers (even symmetry; values bit-identical)
    {
      const float2 v0 = make_float2(pw0 * 1024.0f, pf0);
      const float2 v1 = make_float2(pw1 * 1024.0f, pf1);
      A[tid]       = v0;                        // k2 = tid
      A[tid + 256] = v1;                        // k2 = tid+256
      if (tid > 0) A[1024 - tid] = v0;          // k2 in 769..1023, km = tid
      A[768 - tid] = v1;                        // k2 in 513..768, km = tid+256
    }
    __syncthreads();   // all Bb reads done; A ready for fft2

    fft1024p(A, Bb, tw, tid);  // Bb[n].x = 2^20*ac_w[n], Bb[n].y = 1024*ac_f[n]

    float pv = -3.0e38f;
    int   pl = 1 << 30;
    for (int l = 44 + tid; l <= 441; l += 256) {
      const float v = Bb[l].y;
      if (v > pv) { pv = v; pl = l; }
    }
    #pragma unroll
    for (int m = 1; m < 64; m <<= 1) {
      const float ov = __shfl_xor(pv, m, 64);
      const int   ol = __shfl_xor(pl, m, 64);
      if (ov > pv || (ov == pv && ol < pl)) { pv = ov; pl = ol; }
    }
    cs0 = waveReduceSum(cs0);
    cs1 = waveReduceSum(cs1);
    if (lane == 0) { sred[w] = pv; sredi[w] = pl; sred[4 + w] = cs0; sred[8 + w] = cs1; }
    const float pwW = myPw * wgt462;
    #pragma unroll
    for (int l = 0; l < 11; ++l) {
      const float t = waveReduceSum(pwW * ctab[l]);
      if (lane == 0) aprt[w][l] = t;
    }
    __syncthreads();

    if (tid == 0) {
      float bv = sred[0]; int bl = sredi[0];
      #pragma unroll
      for (int q = 1; q < 4; ++q)
        if (sred[q] > bv || (sred[q] == bv && sredi[q] < bl)) { bv = sred[q]; bl = sredi[q]; }
      const float ac0  = Bb[0].y * (1.0f / 1024.0f);
      const float peak = bv * (1.0f / 1024.0f);
      const float nccf = peak / (ac0 + 1e-9f);
      out[PITCH_OFF + fg] = logf(22050.0f / (float)bl);
      out[VOI_OFF + fg]   = (nccf > 0.3f) ? 1.0f : 0.0f;
      out[nccf_off + fg]  = nccf;
      out[EN_OFF + fg]    = 10.0f * log10f(ac0 + 1e-10f);    // Parseval
      const float c0 = sred[4] + sred[5] + sred[6] + sred[7];
      const float c1 = sred[8] + sred[9] + sred[10] + sred[11];
      out[CEN_OFF + fg]   = c1 / (c0 + 1e-10f);
      const float a0 = aprt[0][0] + aprt[1][0] + aprt[2][0] + aprt[3][0];
      const float a1 = aprt[0][1] + aprt[1][1] + aprt[2][1] + aprt[3][1];
      out[TILT_OFF + fg]  = a1 / (a0 + 1e-10f);
    }
    if (tid < 11)
      ws[(size_t)fg * 42 + 31 + tid] =
          aprt[0][tid] + aprt[1][tid] + aprt[2][tid] + aprt[3][tid];
    if (tid < 31)
      ws[(size_t)fg * 42 + tid] = Bb[tid].x * (1.0f / 1048576.0f);
  }
}

// ============ K2: tails, 24 frames/block (4 waves x 6 ten-lane groups) ============
__global__ void __launch_bounds__(256)
feat_tail(const float* __restrict__ ws, float* __restrict__ out) {
  const int tid  = threadIdx.x;
  const int w    = tid >> 6;
  const int lane = tid & 63;
  const int g    = lane / 10;            // 0..6 (g=6: lanes 60-63, inactive)
  const int ri   = lane - g * 10;
  const int gbase = g * 10;
  int frame = blockIdx.x * 24 + w * 6 + ((g < 6) ? g : 5);
  const bool act = (g < 6) && (frame < NFTOT);
  if (frame >= NFTOT) frame = NFTOT - 1;

  float st[42];
  #pragma unroll
  for (int j = 0; j < 42; ++j) st[j] = ws[(size_t)frame * 42 + j];

  tail_group(st, out, frame, ri, gbase, act);
}

// ============ Fallback: verbatim R15 monolith (proven PASS) ============
__global__ void __launch_bounds__(256, 8)
feat_mono_fb(const float* __restrict__ x, float* __restrict__ out,
             const int xds_pf, const int nccf_off) {
  __shared__ float2 A[1024];
  __shared__ float2 Bb[1024];
  __shared__ float2 tw[256];
  __shared__ float  sred[12];
  __shared__ int    sredi[4];
  __shared__ float  stash[FPB][42];
  __shared__ float  aprt[4][11];

  const int tid   = threadIdx.x;
  const int w     = tid >> 6;
  const int lane  = tid & 63;
  const int fbase = blockIdx.x * FPB;
  const int np    = (fbase + FPB <= NFTOT) ? FPB : (NFTOT - fbase);

  {
    const float th = (float)tid * (6.2831853071795864769f / 1024.0f);
    float sn, cn;
    sincosf(th, &sn, &cn);
    tw[tid] = make_float2(cn, sn);
  }
  float wv[4];
  float wsq = 0.0f;
  #pragma unroll
  for (int q = 0; q < 4; ++q) {
    const int n = tid + q * 256;
    const float th = (float)n * (6.2831853071795864769f / 1023.0f);
    const float wn = 0.42f - 0.5f * cosf(th) + 0.08f * cosf(2.0f * th);
    wv[q] = wn;
    wsq += wn * wn;
  }
  float ctab[11];
  #pragma unroll
  for (int l = 0; l < 11; ++l)
    ctab[l] = cosf((float)(tid * l) * (6.2831853071795864769f / 462.0f));
  const float wgt462 = ((tid == 0 || tid == 231) ? 1.0f : 2.0f) * (1.0f / 462.0f);
  __syncthreads();
  const float invn = 1.0f / sqrtf(blockReduceSum(wsq, sred));

  #pragma unroll 1
  for (int p = 0; p < np; ++p) {
    const int fg = fbase + p;
    const int bb = fg / NFRAME;
    const int fr = fg - bb * NFRAME;
    const float* xb = x + (size_t)bb * NSAMP;

    #pragma unroll
    for (int q = 0; q < 4; ++q) {
      const int n = tid + q * 256;
      const int g = fr * 256 + n - 512;
      const float xv = (g >= 0 && g < NSAMP) ? xb[g] : 0.0f;
      A[n] = make_float2(xv * wv[q] * invn, xv);
    }
    __syncthreads();

    fft1024p(A, Bb, tw, tid);

    float cs0 = 0.0f, cs1 = 0.0f;
    float myPw = 0.0f;
    {
      const int k = tid;
      const float2 Zk = Bb[k];
      const float2 Zn = Bb[(1024 - k) & 1023];
      const float xwr = 0.5f * (Zk.x + Zn.x);
      const float xwi = 0.5f * (Zk.y - Zn.y);
      const float xfr = 0.5f * (Zk.y + Zn.y);
      const float xfi = -0.5f * (Zk.x - Zn.x);
      const float pw = xwr * xwr + xwi * xwi;
      const float pf = xfr * xfr + xfi * xfi;
      const float mg = sqrtf(pf);
      cs0 += mg;
      cs1 += mg * ((float)k * (22050.0f / 1024.0f));
      if (k < 232) {
        myPw = pw;
        if (xds_pf == 232) {
          out[XDS_OFF + (size_t)fg * 232 + k] = xwr;
        } else {
          ((float2*)(out + XDS_OFF))[(size_t)fg * 232 + k] = make_float2(xwr, xwi);
        }
      }
    }
    {
      const int k = tid + 256;
      const float2 Zk = Bb[k];
      const float2 Zn = Bb[1024 - k];
      const float xfr = 0.5f * (Zk.y + Zn.y);
      const float xfi = -0.5f * (Zk.x - Zn.x);
      const float pf = xfr * xfr + xfi * xfi;
      const float mg = sqrtf(pf);
      cs0 += mg;
      cs1 += mg * ((float)k * (22050.0f / 1024.0f));
    }
    if (tid == 0) {
      const int k = 512;
      const float2 Zk = Bb[k];
      const float2 Zn = Bb[512];
      const float xfr = 0.5f * (Zk.y + Zn.y);
      const float xfi = -0.5f * (Zk.x - Zn.x);
      const float pf = xfr * xfr + xfi * xfi;
      const float mg = sqrtf(pf);
      cs0 += mg;
      cs1 += mg * ((float)k * (22050.0f / 1024.0f));
    }

    #pragma unroll
    for (int q = 0; q < 4; ++q) {
      const int k2 = tid + q * 256;
      const int km = (k2 <= 512) ? k2 : (1024 - k2);
      const float2 Zk = Bb[km];
      const float2 Zn = Bb[(1024 - km) & 1023];
      const float xwr = 0.5f * (Zk.x + Zn.x);
      const float xwi = 0.5f * (Zk.y - Zn.y);
      const float xfr = 0.5f * (Zk.y + Zn.y);
      const float xfi = -0.5f * (Zk.x - Zn.x);
      const float pw = xwr * xwr + xwi * xwi;
      const float pf = xfr * xfr + xfi * xfi;
      A[k2] = make_float2(pw * 1024.0f, pf);
    }
    __syncthreads();

    fft1024p(A, Bb, tw, tid);

    float pv = -3.0e38f;
    int   pl = 1 << 30;
    for (int l = 44 + tid; l <= 441; l += 256) {
      const float v = Bb[l].y;
      if (v > pv) { pv = v; pl = l; }
    }
    #pragma unroll
    for (int m = 1; m < 64; m <<= 1) {
      const float ov = __shfl_xor(pv, m, 64);
      const int   ol = __shfl_xor(pl, m, 64);
      if (ov > pv || (ov == pv && ol < pl)) { pv = ov; pl = ol; }
    }
    cs0 = waveReduceSum(cs0);
    cs1 = waveReduceSum(cs1);
    if (lane == 0) { sred[w] = pv; sredi[w] = pl; sred[4 + w] = cs0; sred[8 + w] = cs1; }
    const float pwW = myPw * wgt462;
    #pragma unroll
    for (int l = 0; l < 11; ++l) {
      const float t = waveReduceSum(pwW * ctab[l]);
      if (lane == 0) aprt[w][l] = t;
    }
    __syncthreads();

    if (tid == 0) {
      float bv = sred[0]; int bl = sredi[0];
      #pragma unroll
      for (int q = 1; q < 4; ++q)
        if (sred[q] > bv || (sred[q] == bv && sredi[q] < bl)) { bv = sred[q]; bl = sredi[q]; }
      const float ac0  = Bb[0].y * (1.0f / 1024.0f);
      const float peak = bv * (1.0f / 1024.0f);
      const float nccf = peak / (ac0 + 1e-9f);
      out[PITCH_OFF + fg] = logf(22050.0f / (float)bl);
      out[VOI_OFF + fg]   = (nccf > 0.3f) ? 1.0f : 0.0f;
      out[nccf_off + fg]  = nccf;
      out[EN_OFF + fg]    = 10.0f * log10f(ac0 + 1e-10f);
      const float c0 = sred[4] + sred[5] + sred[6] + sred[7];
      const float c1 = sred[8] + sred[9] + sred[10] + sred[11];
      out[CEN_OFF + fg]   = c1 / (c0 + 1e-10f);
      const float a0 = aprt[0][0] + aprt[1][0] + aprt[2][0] + aprt[3][0];
      const float a1 = aprt[0][1] + aprt[1][1] + aprt[2][1] + aprt[3][1];
      out[TILT_OFF + fg]  = a1 / (a0 + 1e-10f);
    }
    if (tid < 11)
      stash[p][31 + tid] = aprt[0][tid] + aprt[1][tid] + aprt[2][tid] + aprt[3][tid];
    if (tid < 31) stash[p][tid] = Bb[tid].x * (1.0f / 1048576.0f);
  }
  __syncthreads();

  if (w == 0) {
    const int g     = lane / 10;
    const int ri    = lane - g * 10;
    const int gbase = g * 10;
    const int gg    = (g < FPB) ? g : (FPB - 1);
    const bool act  = (g < np);
    const int fg    = fbase + gg;
    tail_group(&stash[gg][0], out, fg, ri, gbase, act);
  }
}

extern "C" void kernel_launch(void* const* d_in, const int* in_sizes, int n_in,
                              void* d_out, int out_size, void* d_ws, size_t ws_size,
                              hipStream_t stream) {
  (void)in_sizes; (void)n_in;
  const float* x = (const float*)d_in[0];
  float* out = (float*)d_out;
  int xds_pf = 232;
  if (out_size >= XDS_OFF + NFTOT * 464 + NFTOT) xds_pf = 464;
  const int nccf_off = XDS_OFF + NFTOT * xds_pf;

  const size_t need = (size_t)NFTOT * 42 * 4;   // 3,472,896 B
  if (d_ws != nullptr && ws_size >= need) {
    float* ws = (float*)d_ws;
    feat_front<<<dim3(NBLK), dim3(256), 0, stream>>>(x, out, ws, xds_pf, nccf_off);
    feat_tail<<<dim3((NFTOT + 23) / 24), dim3(256), 0, stream>>>(ws, out);
  } else {
    feat_mono_fb<<<dim3(NBLK), dim3(256), 0, stream>>>(x, out, xds_pf, nccf_off);
  }
}